// Round 7
// baseline (280.298 us; speedup 1.0000x reference)
//
#include <hip/hip_runtime.h>

#define IN_DIM 4096
#define OUT_DIM 4096
#define M_DIM 8192
#define RANK 32
#define BK 64
#define NT (IN_DIM / BK)   // 64 K-tiles

typedef __bf16 bf16x8 __attribute__((ext_vector_type(8)));
typedef float f32x4 __attribute__((ext_vector_type(4)));

__device__ __forceinline__ unsigned short f2bf(float f) {
  unsigned u = __builtin_bit_cast(unsigned, f);
  u += 0x7FFF + ((u >> 16) & 1);   // round-to-nearest-even
  return (unsigned short)(u >> 16);
}

// ---------------- fused prep: blocks [0,1024) do Wb, [1024,1536) do Xb ----------------
__global__ __launch_bounds__(256) void prep_kernel(
    const float* __restrict__ X, unsigned short* __restrict__ Xb,
    const float* __restrict__ W, const float* __restrict__ A,
    const float* __restrict__ B, unsigned short* __restrict__ Wb) {
  const int tid = threadIdx.x;
  if (blockIdx.x >= 1024) {
    // ---- X cast path ----
    const int idx0 = (blockIdx.x - 1024) * 256 + tid;
    const int stride = 512 * 256;
    const int total4 = (M_DIM * IN_DIM) / 4;
    for (int i = idx0; i < total4; i += stride) {
      const float4 v = reinterpret_cast<const float4*>(X)[i];
      ushort4 o;
      o.x = f2bf(v.x); o.y = f2bf(v.y); o.z = f2bf(v.z); o.w = f2bf(v.w);
      reinterpret_cast<ushort4*>(Xb)[i] = o;
    }
    return;
  }
  // ---- W path: Wb = bf16(W + A @ B^T), rank-32 via one MFMA per fragment ----
  __shared__ unsigned short sA[128][40];
  __shared__ unsigned short sB[128][40];
  const int lane = tid & 63;
  const int wid  = tid >> 6;
  const int wr   = wid >> 1, wc = wid & 1;
  const int li   = lane & 15, kg = lane >> 4;
  const int bRow = (blockIdx.x >> 5) * 128;   // out dim
  const int bCol = (blockIdx.x & 31) * 128;   // in dim

  for (int i = tid; i < 128 * 8; i += 256) {
    const int r = i >> 3, q = i & 7;
    const float4 va = reinterpret_cast<const float4*>(A + (size_t)(bRow + r) * RANK)[q];
    ushort4 oa;
    oa.x = f2bf(va.x); oa.y = f2bf(va.y); oa.z = f2bf(va.z); oa.w = f2bf(va.w);
    *reinterpret_cast<ushort4*>(&sA[r][q * 4]) = oa;
    const float4 vb = reinterpret_cast<const float4*>(B + (size_t)(bCol + r) * RANK)[q];
    ushort4 ob;
    ob.x = f2bf(vb.x); ob.y = f2bf(vb.y); ob.z = f2bf(vb.z); ob.w = f2bf(vb.w);
    *reinterpret_cast<ushort4*>(&sB[r][q * 4]) = ob;
  }
  __syncthreads();

  bf16x8 af[4], bq[4];
#pragma unroll
  for (int m = 0; m < 4; ++m)
    af[m] = *reinterpret_cast<const bf16x8*>(&sA[wr * 64 + m * 16 + li][kg * 8]);
#pragma unroll
  for (int n = 0; n < 4; ++n)
    bq[n] = *reinterpret_cast<const bf16x8*>(&sB[wc * 64 + n * 16 + li][kg * 8]);

  f32x4 acc[4][4];
#pragma unroll
  for (int m = 0; m < 4; ++m)
#pragma unroll
    for (int n = 0; n < 4; ++n) {
      acc[m][n] = f32x4{0.f, 0.f, 0.f, 0.f};
      acc[m][n] = __builtin_amdgcn_mfma_f32_16x16x32_bf16(af[m], bq[n], acc[m][n], 0, 0, 0);
    }

#pragma unroll
  for (int m = 0; m < 4; ++m) {
#pragma unroll
    for (int n = 0; n < 4; ++n) {
      const int col = bCol + wc * 64 + n * 16 + li;
#pragma unroll
      for (int j = 0; j < 4; ++j) {
        const int row = bRow + wr * 64 + m * 16 + kg * 4 + j;
        const size_t idx = (size_t)row * IN_DIM + col;
        Wb[idx] = f2bf(W[idx] + acc[m][n][j]);
      }
    }
  }
}

// ---------------- main GEMM: 256x256, BK=64, 4 windows/tile, frag-prefetch ----------------
// 8 waves (2M x 4N), per-wave 128x64, 16x16x32 MFMA (proven 0-conflict reads).
// Window Wi = { stage-issues ; ds_read issues for MM(W_{i+1}) ; BAR ; MM(Wi) } --
// every MM's fragments were read ONE window earlier, so its lgkm wait is ~free
// and LDS-pipe drain overlaps the previous MM cluster (pipe max, not sum).
// MM decomposition by (A-half h, k-slice ks): MM = af_set(h,ks)[4] x bq_set(ks)[4]
// -> reads/window 8,4,4,8; frag regs = 2 af-sets + 2 bq-sets = 64 VGPR (unchanged).
//   W0: [st1: STAGE B1,A1(t+1)->dn] rd af1<-A0k1, bq1<-k1   | BAR | MM(acc0..3, af0,bq0)
//   W1:                              rd af0<-A1k0            | BAR | MM(acc0..3, af1,bq1)
//   W2: [st2: STAGE A0(t+2)->d]     rd af1<-A1k1; vmcnt(2/0) | BAR | MM(acc4..7, af0,bq0)
//   W3: [st2: STAGE B0(t+2)->d]     [st1: rd af0<-A0k0(dn), bq0<-k0(dn)] | BAR | MM(acc4..7, af1,bq1)
// vmcnt induction: entering W0 outstanding = {A0,B0}(t+1) = 4; +4 (W0) +2 (W2)
// = 10; vmcnt(2) at W2 drains all 8 of tile t+1 -> BAR2 publishes before W3's
// prefetch reads of tile t+1's regions. Steady-state never drains to 0.
__global__ __launch_bounds__(512, 2) void gemm_kernel(
    const unsigned short* __restrict__ Xb, const unsigned short* __restrict__ Wb,
    const float* __restrict__ bias, float* __restrict__ Y) {
  __shared__ unsigned short lds[8][8192];   // 128 KiB
  const int tid  = threadIdx.x;
  const int lane = tid & 63;
  const int wid  = tid >> 6;          // 0..7
  const int wr   = wid >> 2;          // 0..1
  const int wc   = wid & 3;           // 0..3
  const int li   = lane & 15, kg = lane >> 4;

  // XCD-aware bijective swizzle: 512 blocks = 8 XCDs x 64
  const int bid = blockIdx.x;
  const int swz = (bid & 7) * 64 + (bid >> 3);
  const int bx  = swz & 15;           // N tiles: 4096/256 = 16
  const int by  = swz >> 4;           // M tiles: 8192/256 = 32
  const int bRow = by * 256, bCol = bx * 256;

  // ---- staging source addressing: physical chunk p = l*512 + tid;
  //      local row r = p>>3; kc = (p&7)^(r&7)  (XOR chunk swizzle) ----
  const int kcS = (tid & 7) ^ ((tid >> 3) & 7);
  const unsigned short* srcA[2][2];
  const unsigned short* srcB[2][2];
#pragma unroll
  for (int h = 0; h < 2; ++h)
#pragma unroll
    for (int l = 0; l < 2; ++l) {
      const int gA = l * 128 + h * 64 + (tid >> 3);
      const int gB = (l * 2 + (tid >> 8)) * 64 + h * 32 + ((tid >> 3) & 31);
      srcA[h][l] = Xb + (size_t)(bRow + gA) * IN_DIM + kcS * 8;
      srcB[h][l] = Wb + (size_t)(bCol + gB) * IN_DIM + kcS * 8;
    }
  char* const ldsRaw = (char*)&lds[0][0];

#define GLD(src, dstoff)                                                       \
  __builtin_amdgcn_global_load_lds(                                            \
      (const __attribute__((address_space(1))) unsigned int*)(src),            \
      (__attribute__((address_space(3))) unsigned int*)(ldsRaw + (dstoff)),    \
      16, 0, 0)
#define STAGE_A(s, h)                                                          \
  do {                                                                         \
    const int q_ = (((s) & 1) << 2) + (h);                                     \
    GLD(srcA[h][0] + (s) * BK, q_ * 16384 + tid * 16);                         \
    GLD(srcA[h][1] + (s) * BK, q_ * 16384 + 8192 + tid * 16);                  \
  } while (0)
#define STAGE_B(s, h)                                                          \
  do {                                                                         \
    const int q_ = (((s) & 1) << 2) + 2 + (h);                                 \
    GLD(srcB[h][0] + (s) * BK, q_ * 16384 + tid * 16);                         \
    GLD(srcB[h][1] + (s) * BK, q_ * 16384 + 8192 + tid * 16);                  \
  } while (0)
#define BAR() __builtin_amdgcn_s_barrier()

  // ---- fragment read addressing (proven conflict-free pattern) ----
  const int rowAoff = (wr * 64 + li) * 64;
  const int rowBoff = (wc * 32 + li) * 64;
  int kx[2];
  kx[0] = ((0 * 4 + kg) ^ (li & 7)) * 8;
  kx[1] = ((1 * 4 + kg) ^ (li & 7)) * 8;

  bf16x8 af0[4], af1[4], bq0[4], bq1[4];
  f32x4 acc[8][4];
#pragma unroll
  for (int m = 0; m < 8; ++m)
#pragma unroll
    for (int n = 0; n < 4; ++n) acc[m][n] = f32x4{0.f, 0.f, 0.f, 0.f};

#define RD_AF(dst, dsel, h, ks)                                                \
  do {                                                                         \
    const unsigned short* a_ = &lds[((dsel) << 2) + (h)][0] + rowAoff;         \
    _Pragma("unroll") for (int mq = 0; mq < 4; ++mq)                           \
      dst[mq] = *reinterpret_cast<const bf16x8*>(a_ + mq * 1024 + kx[ks]);     \
  } while (0)
#define RD_BQ(dst, dsel, ks)                                                   \
  do {                                                                         \
    const unsigned short* b0_ = &lds[((dsel) << 2) + 2][0] + rowBoff;          \
    const unsigned short* b1_ = &lds[((dsel) << 2) + 3][0] + rowBoff;          \
    dst[0] = *reinterpret_cast<const bf16x8*>(b0_ + kx[ks]);                   \
    dst[1] = *reinterpret_cast<const bf16x8*>(b0_ + 1024 + kx[ks]);            \
    dst[2] = *reinterpret_cast<const bf16x8*>(b1_ + kx[ks]);                   \
    dst[3] = *reinterpret_cast<const bf16x8*>(b1_ + 1024 + kx[ks]);            \
  } while (0)
#define MM(base, afv, bqv)                                                     \
  do {                                                                         \
    __builtin_amdgcn_s_setprio(1);                                             \
    _Pragma("unroll") for (int mq = 0; mq < 4; ++mq)                           \
      _Pragma("unroll") for (int nq = 0; nq < 4; ++nq)                         \
        acc[(base) + mq][nq] = __builtin_amdgcn_mfma_f32_16x16x32_bf16(        \
            afv[mq], bqv[nq], acc[(base) + mq][nq], 0, 0, 0);                  \
    __builtin_amdgcn_s_setprio(0);                                             \
  } while (0)

  // ---- prologue: stage tile 0 (8 loads) + A0,B0 of tile 1 (4 loads);
  //      publish tile 0; prefetch first window's fragments ----
  STAGE_A(0, 0); STAGE_B(0, 0); STAGE_A(0, 1); STAGE_B(0, 1);
  STAGE_A(1, 0); STAGE_B(1, 0);
  asm volatile("s_waitcnt vmcnt(4)" ::: "memory");
  BAR();
  RD_AF(af0, 0, 0, 0);
  RD_BQ(bq0, 0, 0);

  for (int t = 0; t < NT; ++t) {
    const int dcur = t & 1;
    const int dn   = dcur ^ 1;
    const bool st1 = (t + 1 < NT), st2 = (t + 2 < NT);
    // W0
    if (st1) { STAGE_B(t + 1, 1); STAGE_A(t + 1, 1); }
    RD_AF(af1, dcur, 0, 1);
    RD_BQ(bq1, dcur, 1);
    BAR();
    MM(0, af0, bq0);
    // W1
    RD_AF(af0, dcur, 1, 0);
    BAR();
    MM(0, af1, bq1);
    // W2
    if (st2) STAGE_A(t + 2, 0);
    RD_AF(af1, dcur, 1, 1);
    if (st2) asm volatile("s_waitcnt vmcnt(2)" ::: "memory");
    else     asm volatile("s_waitcnt vmcnt(0)" ::: "memory");
    BAR();
    MM(4, af0, bq0);
    // W3
    if (st2) STAGE_B(t + 2, 0);
    if (st1) { RD_AF(af0, dn, 0, 0); RD_BQ(bq0, dn, 0); }
    BAR();
    MM(4, af1, bq1);
  }
#undef GLD
#undef STAGE_A
#undef STAGE_B
#undef BAR
#undef RD_AF
#undef RD_BQ
#undef MM

  // ---- epilogue: C/D layout col = li, row = kg*4 + j (m89-verified) ----
#pragma unroll
  for (int nf = 0; nf < 4; ++nf) {
    const int col = bCol + wc * 64 + nf * 16 + li;
    const float bv = bias[col];
#pragma unroll
    for (int mf = 0; mf < 8; ++mf) {
      const int row0 = bRow + wr * 128 + mf * 16 + kg * 4;
#pragma unroll
      for (int j = 0; j < 4; ++j)
        Y[(size_t)(row0 + j) * OUT_DIM + col] = acc[mf][nf][j] + bv;
    }
  }
}

extern "C" void kernel_launch(void* const* d_in, const int* in_sizes, int n_in,
                              void* d_out, int out_size, void* d_ws, size_t ws_size,
                              hipStream_t stream) {
  const float* x    = (const float*)d_in[0];
  const float* w    = (const float*)d_in[1];
  const float* bias = (const float*)d_in[2];
  const float* A    = (const float*)d_in[3];
  const float* B    = (const float*)d_in[4];
  float* y = (float*)d_out;

  const size_t xb_bytes = (size_t)M_DIM * IN_DIM * 2;          // 64 MiB
  const size_t wb_bytes = (size_t)OUT_DIM * IN_DIM * 2;        // 32 MiB
  if (ws_size < xb_bytes + wb_bytes) return;

  unsigned short* Xb = (unsigned short*)d_ws;
  unsigned short* Wb = (unsigned short*)((char*)d_ws + xb_bytes);

  prep_kernel<<<1536, 256, 0, stream>>>(x, Xb, w, A, B, Wb);
  gemm_kernel<<<(M_DIM / 256) * (OUT_DIM / 256), 512, 0, stream>>>(Xb, Wb, bias, y);
}

// Round 8
// 279.810 us; speedup vs baseline: 1.0017x; 1.0017x over previous
//
#include <hip/hip_runtime.h>

#define IN_DIM 4096
#define OUT_DIM 4096
#define M_DIM 8192
#define RANK 32
#define BK 64
#define NT (IN_DIM / BK)   // 64 K-tiles

typedef __bf16 bf16x8 __attribute__((ext_vector_type(8)));
typedef float f32x4 __attribute__((ext_vector_type(4)));

__device__ __forceinline__ unsigned short f2bf(float f) {
  unsigned u = __builtin_bit_cast(unsigned, f);
  u += 0x7FFF + ((u >> 16) & 1);   // round-to-nearest-even
  return (unsigned short)(u >> 16);
}

// ---------------- fused prep: blocks [0,1024) do Wb, [1024,1536) do Xb ----------------
__global__ __launch_bounds__(256) void prep_kernel(
    const float* __restrict__ X, unsigned short* __restrict__ Xb,
    const float* __restrict__ W, const float* __restrict__ A,
    const float* __restrict__ B, unsigned short* __restrict__ Wb) {
  const int tid = threadIdx.x;
  if (blockIdx.x >= 1024) {
    // ---- X cast path ----
    const int idx0 = (blockIdx.x - 1024) * 256 + tid;
    const int stride = 512 * 256;
    const int total4 = (M_DIM * IN_DIM) / 4;
    for (int i = idx0; i < total4; i += stride) {
      const float4 v = reinterpret_cast<const float4*>(X)[i];
      ushort4 o;
      o.x = f2bf(v.x); o.y = f2bf(v.y); o.z = f2bf(v.z); o.w = f2bf(v.w);
      reinterpret_cast<ushort4*>(Xb)[i] = o;
    }
    return;
  }
  // ---- W path: Wb = bf16(W + A @ B^T), rank-32 via one MFMA per fragment ----
  __shared__ unsigned short sA[128][40];
  __shared__ unsigned short sB[128][40];
  const int lane = tid & 63;
  const int wid  = tid >> 6;
  const int wr   = wid >> 1, wc = wid & 1;
  const int li   = lane & 15, kg = lane >> 4;
  const int bRow = (blockIdx.x >> 5) * 128;   // out dim
  const int bCol = (blockIdx.x & 31) * 128;   // in dim

  for (int i = tid; i < 128 * 8; i += 256) {
    const int r = i >> 3, q = i & 7;
    const float4 va = reinterpret_cast<const float4*>(A + (size_t)(bRow + r) * RANK)[q];
    ushort4 oa;
    oa.x = f2bf(va.x); oa.y = f2bf(va.y); oa.z = f2bf(va.z); oa.w = f2bf(va.w);
    *reinterpret_cast<ushort4*>(&sA[r][q * 4]) = oa;
    const float4 vb = reinterpret_cast<const float4*>(B + (size_t)(bCol + r) * RANK)[q];
    ushort4 ob;
    ob.x = f2bf(vb.x); ob.y = f2bf(vb.y); ob.z = f2bf(vb.z); ob.w = f2bf(vb.w);
    *reinterpret_cast<ushort4*>(&sB[r][q * 4]) = ob;
  }
  __syncthreads();

  bf16x8 af[4], bq[4];
#pragma unroll
  for (int m = 0; m < 4; ++m)
    af[m] = *reinterpret_cast<const bf16x8*>(&sA[wr * 64 + m * 16 + li][kg * 8]);
#pragma unroll
  for (int n = 0; n < 4; ++n)
    bq[n] = *reinterpret_cast<const bf16x8*>(&sB[wc * 64 + n * 16 + li][kg * 8]);

  f32x4 acc[4][4];
#pragma unroll
  for (int m = 0; m < 4; ++m)
#pragma unroll
    for (int n = 0; n < 4; ++n) {
      acc[m][n] = f32x4{0.f, 0.f, 0.f, 0.f};
      acc[m][n] = __builtin_amdgcn_mfma_f32_16x16x32_bf16(af[m], bq[n], acc[m][n], 0, 0, 0);
    }

#pragma unroll
  for (int m = 0; m < 4; ++m) {
#pragma unroll
    for (int n = 0; n < 4; ++n) {
      const int col = bCol + wc * 64 + n * 16 + li;
#pragma unroll
      for (int j = 0; j < 4; ++j) {
        const int row = bRow + wr * 64 + m * 16 + kg * 4 + j;
        const size_t idx = (size_t)row * IN_DIM + col;
        Wb[idx] = f2bf(W[idx] + acc[m][n][j]);
      }
    }
  }
}

// ---------------- main GEMM: 256x256, BK=64, 4 windows/tile, PINNED frag-prefetch ----------------
// Round-7 schedule + sched_barrier(0) on both sides of every s_barrier.
// Rationale (round-7 post-mortem): LLVM freely sinks ds_reads across raw
// s_barrier toward their uses, collapsing the prefetch pipeline back into
// read->wait->MM serialization (round 6 == round 7 == 1074 cyc/window =
// 621 MFMA + 576 LDS serialized). sched_barrier(0) pins: reads stay in the
// window that issues them; MM stays after the barrier. Every MM's fragments
// were read ONE window earlier -> its lgkm wait tolerates the 4-8 newer
// prefetch reads (compiler emits counted lgkmcnt) -> LDS drain overlaps MM.
//   W0: [st1: STAGE B1,A1(t+1)->dn] rd af1<-A0k1, bq1<-k1   | BAR | MM(acc0..3, af0,bq0)
//   W1:                              rd af0<-A1k0            | BAR | MM(acc0..3, af1,bq1)
//   W2: [st2: STAGE A0(t+2)->d]     rd af1<-A1k1; vmcnt(2/0) | BAR | MM(acc4..7, af0,bq0)
//   W3: [st2: STAGE B0(t+2)->d]     [st1: rd af0<-A0k0(dn), bq0<-k0(dn)] | BAR | MM(acc4..7, af1,bq1)
// WAR/RAW audit (unchanged from round 7): every stage-write >=1 barrier after
// the MM whose lgkm-wait retires that region's last read; W3's cross-tile
// prefetch reads target regions published by W2's vmcnt(2)+BAR.
// vmcnt induction: entering W0 outstanding=4; +4(W0)+2(W2)=10; vmcnt(2)
// drains all 8 of tile t+1. Steady state never drains to 0.
__global__ __launch_bounds__(512, 2) void gemm_kernel(
    const unsigned short* __restrict__ Xb, const unsigned short* __restrict__ Wb,
    const float* __restrict__ bias, float* __restrict__ Y) {
  __shared__ unsigned short lds[8][8192];   // 128 KiB
  const int tid  = threadIdx.x;
  const int lane = tid & 63;
  const int wid  = tid >> 6;          // 0..7
  const int wr   = wid >> 2;          // 0..1
  const int wc   = wid & 3;           // 0..3
  const int li   = lane & 15, kg = lane >> 4;

  // XCD-aware bijective swizzle: 512 blocks = 8 XCDs x 64
  const int bid = blockIdx.x;
  const int swz = (bid & 7) * 64 + (bid >> 3);
  const int bx  = swz & 15;           // N tiles: 4096/256 = 16
  const int by  = swz >> 4;           // M tiles: 8192/256 = 32
  const int bRow = by * 256, bCol = bx * 256;

  // ---- staging source addressing: physical chunk p = l*512 + tid;
  //      local row r = p>>3; kc = (p&7)^(r&7)  (XOR chunk swizzle) ----
  const int kcS = (tid & 7) ^ ((tid >> 3) & 7);
  const unsigned short* srcA[2][2];
  const unsigned short* srcB[2][2];
#pragma unroll
  for (int h = 0; h < 2; ++h)
#pragma unroll
    for (int l = 0; l < 2; ++l) {
      const int gA = l * 128 + h * 64 + (tid >> 3);
      const int gB = (l * 2 + (tid >> 8)) * 64 + h * 32 + ((tid >> 3) & 31);
      srcA[h][l] = Xb + (size_t)(bRow + gA) * IN_DIM + kcS * 8;
      srcB[h][l] = Wb + (size_t)(bCol + gB) * IN_DIM + kcS * 8;
    }
  char* const ldsRaw = (char*)&lds[0][0];

#define GLD(src, dstoff)                                                       \
  __builtin_amdgcn_global_load_lds(                                            \
      (const __attribute__((address_space(1))) unsigned int*)(src),            \
      (__attribute__((address_space(3))) unsigned int*)(ldsRaw + (dstoff)),    \
      16, 0, 0)
#define STAGE_A(s, h)                                                          \
  do {                                                                         \
    const int q_ = (((s) & 1) << 2) + (h);                                     \
    GLD(srcA[h][0] + (s) * BK, q_ * 16384 + tid * 16);                         \
    GLD(srcA[h][1] + (s) * BK, q_ * 16384 + 8192 + tid * 16);                  \
  } while (0)
#define STAGE_B(s, h)                                                          \
  do {                                                                         \
    const int q_ = (((s) & 1) << 2) + 2 + (h);                                 \
    GLD(srcB[h][0] + (s) * BK, q_ * 16384 + tid * 16);                         \
    GLD(srcB[h][1] + (s) * BK, q_ * 16384 + 8192 + tid * 16);                  \
  } while (0)
#define BAR() __builtin_amdgcn_s_barrier()
#define SCHED() __builtin_amdgcn_sched_barrier(0)

  // ---- fragment read addressing (proven conflict-free pattern) ----
  const int rowAoff = (wr * 64 + li) * 64;
  const int rowBoff = (wc * 32 + li) * 64;
  int kx[2];
  kx[0] = ((0 * 4 + kg) ^ (li & 7)) * 8;
  kx[1] = ((1 * 4 + kg) ^ (li & 7)) * 8;

  bf16x8 af0[4], af1[4], bq0[4], bq1[4];
  f32x4 acc[8][4];
#pragma unroll
  for (int m = 0; m < 8; ++m)
#pragma unroll
    for (int n = 0; n < 4; ++n) acc[m][n] = f32x4{0.f, 0.f, 0.f, 0.f};

#define RD_AF(dst, dsel, h, ks)                                                \
  do {                                                                         \
    const unsigned short* a_ = &lds[((dsel) << 2) + (h)][0] + rowAoff;         \
    _Pragma("unroll") for (int mq = 0; mq < 4; ++mq)                           \
      dst[mq] = *reinterpret_cast<const bf16x8*>(a_ + mq * 1024 + kx[ks]);     \
  } while (0)
#define RD_BQ(dst, dsel, ks)                                                   \
  do {                                                                         \
    const unsigned short* b0_ = &lds[((dsel) << 2) + 2][0] + rowBoff;          \
    const unsigned short* b1_ = &lds[((dsel) << 2) + 3][0] + rowBoff;          \
    dst[0] = *reinterpret_cast<const bf16x8*>(b0_ + kx[ks]);                   \
    dst[1] = *reinterpret_cast<const bf16x8*>(b0_ + 1024 + kx[ks]);            \
    dst[2] = *reinterpret_cast<const bf16x8*>(b1_ + kx[ks]);                   \
    dst[3] = *reinterpret_cast<const bf16x8*>(b1_ + 1024 + kx[ks]);            \
  } while (0)
#define MM(base, afv, bqv)                                                     \
  do {                                                                         \
    __builtin_amdgcn_s_setprio(1);                                             \
    _Pragma("unroll") for (int mq = 0; mq < 4; ++mq)                           \
      _Pragma("unroll") for (int nq = 0; nq < 4; ++nq)                         \
        acc[(base) + mq][nq] = __builtin_amdgcn_mfma_f32_16x16x32_bf16(        \
            afv[mq], bqv[nq], acc[(base) + mq][nq], 0, 0, 0);                  \
    __builtin_amdgcn_s_setprio(0);                                             \
  } while (0)

  // ---- prologue: stage tile 0 (8 loads) + A0,B0 of tile 1 (4 loads);
  //      publish tile 0; prefetch first window's fragments ----
  STAGE_A(0, 0); STAGE_B(0, 0); STAGE_A(0, 1); STAGE_B(0, 1);
  STAGE_A(1, 0); STAGE_B(1, 0);
  asm volatile("s_waitcnt vmcnt(4)" ::: "memory");
  BAR();
  RD_AF(af0, 0, 0, 0);
  RD_BQ(bq0, 0, 0);

  for (int t = 0; t < NT; ++t) {
    const int dcur = t & 1;
    const int dn   = dcur ^ 1;
    const bool st1 = (t + 1 < NT), st2 = (t + 2 < NT);
    // W0
    if (st1) { STAGE_B(t + 1, 1); STAGE_A(t + 1, 1); }
    RD_AF(af1, dcur, 0, 1);
    RD_BQ(bq1, dcur, 1);
    SCHED();
    BAR();
    SCHED();
    MM(0, af0, bq0);
    // W1
    RD_AF(af0, dcur, 1, 0);
    SCHED();
    BAR();
    SCHED();
    MM(0, af1, bq1);
    // W2
    if (st2) STAGE_A(t + 2, 0);
    RD_AF(af1, dcur, 1, 1);
    if (st2) asm volatile("s_waitcnt vmcnt(2)" ::: "memory");
    else     asm volatile("s_waitcnt vmcnt(0)" ::: "memory");
    SCHED();
    BAR();
    SCHED();
    MM(4, af0, bq0);
    // W3
    if (st2) STAGE_B(t + 2, 0);
    if (st1) { RD_AF(af0, dn, 0, 0); RD_BQ(bq0, dn, 0); }
    SCHED();
    BAR();
    SCHED();
    MM(4, af1, bq1);
  }
#undef GLD
#undef STAGE_A
#undef STAGE_B
#undef BAR
#undef SCHED
#undef RD_AF
#undef RD_BQ
#undef MM

  // ---- epilogue: C/D layout col = li, row = kg*4 + j (m89-verified) ----
#pragma unroll
  for (int nf = 0; nf < 4; ++nf) {
    const int col = bCol + wc * 64 + nf * 16 + li;
    const float bv = bias[col];
#pragma unroll
    for (int mf = 0; mf < 8; ++mf) {
      const int row0 = bRow + wr * 128 + mf * 16 + kg * 4;
#pragma unroll
      for (int j = 0; j < 4; ++j)
        Y[(size_t)(row0 + j) * OUT_DIM + col] = acc[mf][nf][j] + bv;
    }
  }
}

extern "C" void kernel_launch(void* const* d_in, const int* in_sizes, int n_in,
                              void* d_out, int out_size, void* d_ws, size_t ws_size,
                              hipStream_t stream) {
  const float* x    = (const float*)d_in[0];
  const float* w    = (const float*)d_in[1];
  const float* bias = (const float*)d_in[2];
  const float* A    = (const float*)d_in[3];
  const float* B    = (const float*)d_in[4];
  float* y = (float*)d_out;

  const size_t xb_bytes = (size_t)M_DIM * IN_DIM * 2;          // 64 MiB
  const size_t wb_bytes = (size_t)OUT_DIM * IN_DIM * 2;        // 32 MiB
  if (ws_size < xb_bytes + wb_bytes) return;

  unsigned short* Xb = (unsigned short*)d_ws;
  unsigned short* Wb = (unsigned short*)((char*)d_ws + xb_bytes);

  prep_kernel<<<1536, 256, 0, stream>>>(x, Xb, w, A, B, Wb);
  gemm_kernel<<<(M_DIM / 256) * (OUT_DIM / 256), 512, 0, stream>>>(Xb, Wb, bias, y);
}